// Round 1
// baseline (68.348 us; speedup 1.0000x reference)
//
#include <hip/hip_runtime.h>

// Problem: attn [B=64, N=1024, N=1024] f32.
// For each b, each diagonal offset k=1..N-2: unbiased std of attn[b,i,i+k]
// (i=0..N-1-k), scaled by (N-k)/5. Mean over k, then over b. Scalar f32 out.
//
// Pass 1: per-(chunk,b,k) partial sum / sumsq. Thread t owns fixed offsets
//         k = 1+t and 513+t for every row -> register accumulators, coalesced
//         reads (row segment is contiguous), coalesced partial stores.
// Pass 2: reduce 8 chunk partials per (b,k), apply std formula, per-b mean.
// Pass 3: mean over b -> d_out[0].
//
// Workspace: 2 * (8*64*1024) f32 partials (4 MB) + 64 f32 per-b results.

#define NN 1024
#define NB 64
#define RCH 8          // row chunks per sample (rows interleaved mod RCH)
#define P1_T 512       // pass-1 block size

__global__ __launch_bounds__(P1_T) void diag_pass1(
    const float* __restrict__ attn,
    float* __restrict__ ws_sum,
    float* __restrict__ ws_sq) {
  const int b = blockIdx.x >> 3;   // / RCH
  const int c = blockIdx.x & 7;    // % RCH
  const int t = threadIdx.x;
  const float* __restrict__ base = attn + (size_t)b * NN * NN;

  const int ka = 1 + t;            // 1..512
  const int kb = 513 + t;          // 513..1024 (1024 invalid, guarded)
  float s1a = 0.f, s2a = 0.f, s1b = 0.f, s2b = 0.f;

  #pragma unroll 4
  for (int i = c; i < NN; i += RCH) {
    const float* __restrict__ row = base + (size_t)i * (NN + 1); // &attn[b][i][i]
    const int lim = NN - i;        // valid k satisfies k < lim
    if (ka < lim) { float x = row[ka]; s1a += x; s2a += x * x; }
    if (kb < lim) { float x = row[kb]; s1b += x; s2b += x * x; }
  }

  // Layout [c][b][k]: consecutive t -> consecutive k -> coalesced stores.
  const size_t o = ((size_t)c * NB + b) * NN;
  ws_sum[o + ka] = s1a;
  ws_sq [o + ka] = s2a;
  if (kb < NN) {
    ws_sum[o + kb] = s1b;
    ws_sq [o + kb] = s2b;
  }
}

__global__ __launch_bounds__(256) void diag_pass2(
    const float* __restrict__ ws_sum,
    const float* __restrict__ ws_sq,
    float* __restrict__ ws_b) {
  const int b = blockIdx.x;
  const int t = threadIdx.x;
  float acc = 0.f;

  for (int k = 1 + t; k <= NN - 2; k += 256) {
    float s1 = 0.f, s2 = 0.f;
    #pragma unroll
    for (int c = 0; c < RCH; ++c) {
      const size_t o = ((size_t)c * NB + b) * NN + k;
      s1 += ws_sum[o];
      s2 += ws_sq[o];
    }
    const float n = (float)(NN - k);          // >= 2 for k <= N-2
    const float mean = s1 / n;
    const float var = fmaxf(s2 - n * mean * mean, 0.f) / (n - 1.f);
    acc += sqrtf(var) * (n * 0.2f);           // std * (N-k)/5
  }

  __shared__ float red[256];
  red[t] = acc;
  __syncthreads();
  #pragma unroll
  for (int s = 128; s > 0; s >>= 1) {
    if (t < s) red[t] += red[t + s];
    __syncthreads();
  }
  if (t == 0) ws_b[b] = red[0] * (1.0f / 1022.0f);
}

__global__ __launch_bounds__(64) void diag_pass3(
    const float* __restrict__ ws_b,
    float* __restrict__ out) {
  const int t = threadIdx.x;     // exactly one wave of 64
  float v = ws_b[t];
  #pragma unroll
  for (int s = 32; s > 0; s >>= 1) v += __shfl_down(v, s);
  if (t == 0) out[0] = v * (1.0f / 64.0f);
}

extern "C" void kernel_launch(void* const* d_in, const int* in_sizes, int n_in,
                              void* d_out, int out_size, void* d_ws, size_t ws_size,
                              hipStream_t stream) {
  const float* attn = (const float*)d_in[0];
  float* out = (float*)d_out;

  float* ws_sum = (float*)d_ws;                              // 8*64*1024 f32
  float* ws_sq  = ws_sum + (size_t)RCH * NB * NN;            // 8*64*1024 f32
  float* ws_b   = ws_sq  + (size_t)RCH * NB * NN;            // 64 f32
  // total: 4 MB + 256 B

  diag_pass1<<<NB * RCH, P1_T, 0, stream>>>(attn, ws_sum, ws_sq);
  diag_pass2<<<NB, 256, 0, stream>>>(ws_sum, ws_sq, ws_b);
  diag_pass3<<<1, 64, 0, stream>>>(ws_b, out);
}

// Round 2
// 43.344 us; speedup vs baseline: 1.5769x; 1.5769x over previous
//
#include <hip/hip_runtime.h>

// attn [B=64, N=1024, N=1024] f32. Per (b, k=1..1022): unbiased std of the
// k-th super-diagonal scaled by (N-k)/5; mean over k then b -> scalar.
//
// Pass 1 (grid NB*RCH, 256 thr): element (i,k) sits at flat offset
//   b*2^20 + i*1025 + k  ==  (i+k) (mod 4).
// Rows of a block all share i mod 4 (RCH % 4 == 0), so phase p = (-i) mod 4
// (0->4) makes k = p+4t a 16B-aligned float4 window. Thread t keeps 4 fixed-k
// register accumulator pairs; edge elements k=1..p-1 go to threads 249..251.
// Partials stored phase-relative: slot s = k - p (coalesced float4 stores),
// edges at slot 1024+k. Layout: ws[(b*RCH+c)*2*1032], [0..1031]=sum,
// [1032..2063]=sumsq.
//
// Pass 2 (grid NB*4, 256 thr): block (b,kc) reduces RCH chunk partials for
// k = kc*256+t, applies std formula, block-reduces -> part[b*4+kc].
// Pass 3 (1 block, 64 thr): scalar mean.

#define NN 1024
#define NB 64
#define WSTRIDE 1032   // 1024 window slots + 3 edge slots + pad (16B-aligned)

template<int RCH>
__global__ __launch_bounds__(256) void diag_pass1(
    const float* __restrict__ attn, float* __restrict__ ws) {
  const int b = blockIdx.x / RCH;
  const int c = blockIdx.x % RCH;
  const int t = threadIdx.x;
  int p = (4 - (c & 3)) & 3; if (p == 0) p = 4;   // phase: k = p+4t aligned

  const float* __restrict__ base = attn + ((size_t)b << 20);
  const int k0 = p + 4 * t;

  float s1x = 0.f, s1y = 0.f, s1z = 0.f, s1w = 0.f;
  float s2x = 0.f, s2y = 0.f, s2z = 0.f, s2w = 0.f;
  float e1 = 0.f, e2 = 0.f;
  const int ek = t - 248;            // threads 249..251 own edge k = 1..3

  #pragma unroll 4
  for (int i = c; i < NN; i += RCH) {
    const int lim = NN - i;          // element (i,k) valid iff k < lim
    const float* __restrict__ rowd = base + (size_t)i * (NN + 1);
    if (k0 < lim) {
      const float4 v = *reinterpret_cast<const float4*>(rowd + k0);
      const float x0 = v.x;                          // k0 < lim guaranteed
      const float x1 = (k0 + 1 < lim) ? v.y : 0.f;
      const float x2 = (k0 + 2 < lim) ? v.z : 0.f;
      const float x3 = (k0 + 3 < lim) ? v.w : 0.f;
      s1x += x0; s2x += x0 * x0;
      s1y += x1; s2y += x1 * x1;
      s1z += x2; s2z += x2 * x2;
      s1w += x3; s2w += x3 * x3;
    }
    if (ek >= 1 && ek < p && ek < lim) {
      const float x = rowd[ek];
      e1 += x; e2 += x * x;
    }
  }

  float* __restrict__ w1 = ws + (size_t)blockIdx.x * (2 * WSTRIDE);
  float* __restrict__ w2 = w1 + WSTRIDE;
  *reinterpret_cast<float4*>(w1 + 4 * t) = make_float4(s1x, s1y, s1z, s1w);
  *reinterpret_cast<float4*>(w2 + 4 * t) = make_float4(s2x, s2y, s2z, s2w);
  if (ek >= 1 && ek < p) {           // read in pass 2 under the same condition
    w1[1024 + ek] = e1;
    w2[1024 + ek] = e2;
  }
}

template<int RCH>
__global__ __launch_bounds__(256) void diag_pass2(
    const float* __restrict__ ws, float* __restrict__ part) {
  const int b  = blockIdx.x >> 2;
  const int kc = blockIdx.x & 3;
  const int t  = threadIdx.x;
  const int k  = kc * 256 + t;       // 0..1023; valid 1..1022

  float acc = 0.f;
  if (k >= 1 && k <= NN - 2) {
    float s1 = 0.f, s2 = 0.f;
    #pragma unroll
    for (int c = 0; c < RCH; ++c) {
      int p = (4 - (c & 3)) & 3; if (p == 0) p = 4;
      const float* __restrict__ w1 =
          ws + (size_t)(b * RCH + c) * (2 * WSTRIDE);
      const float* __restrict__ w2 = w1 + WSTRIDE;
      const int s = k - p;
      const int idx = (s >= 0) ? s : (1024 + k);   // window or edge slot
      s1 += w1[idx];
      s2 += w2[idx];
    }
    const float n = (float)(NN - k);
    const float mean = s1 / n;
    const float var = fmaxf(s2 - n * mean * mean, 0.f) / (n - 1.f);
    acc = sqrtf(var) * (n * 0.2f);   // std * (N-k)/5
  }

  __shared__ float red[256];
  red[t] = acc;
  __syncthreads();
  #pragma unroll
  for (int s = 128; s > 0; s >>= 1) {
    if (t < s) red[t] += red[t + s];
    __syncthreads();
  }
  if (t == 0) part[blockIdx.x] = red[0];
}

__global__ __launch_bounds__(64) void diag_pass3(
    const float* __restrict__ part, float* __restrict__ out) {
  const int t = threadIdx.x;         // one wave; t = b
  float v = part[4 * t] + part[4 * t + 1] + part[4 * t + 2] + part[4 * t + 3];
  v *= (1.0f / 1022.0f);
  #pragma unroll
  for (int s = 32; s > 0; s >>= 1) v += __shfl_down(v, s);
  if (t == 0) out[0] = v * (1.0f / 64.0f);
}

extern "C" void kernel_launch(void* const* d_in, const int* in_sizes, int n_in,
                              void* d_out, int out_size, void* d_ws, size_t ws_size,
                              hipStream_t stream) {
  const float* attn = (const float*)d_in[0];
  float* out = (float*)d_out;
  float* ws = (float*)d_ws;

  // ws need per RCH: NB*RCH*2*WSTRIDE floats + NB*4 part floats.
  const size_t need16 = ((size_t)NB * 16 * 2 * WSTRIDE + NB * 4) * 4;
  const size_t need8  = ((size_t)NB * 8  * 2 * WSTRIDE + NB * 4) * 4;

  if (ws_size >= need16) {
    constexpr int RCH = 16;
    float* part = ws + (size_t)NB * RCH * 2 * WSTRIDE;
    diag_pass1<RCH><<<NB * RCH, 256, 0, stream>>>(attn, ws);
    diag_pass2<RCH><<<NB * 4, 256, 0, stream>>>(ws, part);
    diag_pass3<<<1, 64, 0, stream>>>(part, out);
  } else if (ws_size >= need8) {
    constexpr int RCH = 8;
    float* part = ws + (size_t)NB * RCH * 2 * WSTRIDE;
    diag_pass1<RCH><<<NB * RCH, 256, 0, stream>>>(attn, ws);
    diag_pass2<RCH><<<NB * 4, 256, 0, stream>>>(ws, part);
    diag_pass3<<<1, 64, 0, stream>>>(part, out);
  } else {
    constexpr int RCH = 4;
    float* part = ws + (size_t)NB * RCH * 2 * WSTRIDE;
    diag_pass1<RCH><<<NB * RCH, 256, 0, stream>>>(attn, ws);
    diag_pass2<RCH><<<NB * 4, 256, 0, stream>>>(ws, part);
    diag_pass3<<<1, 64, 0, stream>>>(part, out);
  }
}